// Round 10
// baseline (158.638 us; speedup 1.0000x reference)
//
#include <hip/hip_runtime.h>
#include <hip/hip_bf16.h>
#include <stdint.h>

// ---------------------------------------------------------------------------
// MF cosine-similarity, test path:
//   C[u][i] = Un[u].Vn[i]; Un/Vn = fp32-normalized rows rounded to bf16.
//
// R10 = R8 (72.5us, best) + ONE change: overlay the epilogue transpose
// buffer on As/Bs (union). ep is only touched after the compute loop's
// final barrier, when As/Bs are dead. LDS 32.5KB -> 16.9KB => 4 -> 8
// resident blocks/CU, doubling the overlap available to cover the per-kt
// vmcnt(0) stage drains and the epilogue barrier chain.
// Evidence so far: nt stores REQUIRE the full-line transpose epilogue
// (R9: nt + scattered-64B = 92us; R8: nt + 512B-contig = 72.5us).
// Loop body, staging, epilogue logic: R8-exact.
// ---------------------------------------------------------------------------

#define LDIM 256
#define NROWS 8192
#define NDIM 8192
#define BM 128
#define BN 128
#define BK 32

typedef __bf16 bf16x8 __attribute__((ext_vector_type(8)));
typedef float f32x4 __attribute__((ext_vector_type(4)));

__device__ __forceinline__ unsigned short f2bf_rne(float f) {
  union { float f; uint32_t u; } c;
  c.f = f;
  uint32_t u = c.u;
  u += 0x7FFFu + ((u >> 16) & 1u);   // round-to-nearest-even
  return (unsigned short)(u >> 16);
}

// One wave per row, both tables in one launch: 256 f32 -> norm -> 256 bf16.
__global__ __launch_bounds__(256) void normalize_both(
    const float* __restrict__ userw, const float* __restrict__ itemw,
    unsigned short* __restrict__ dst) {
  const int wave = threadIdx.x >> 6;
  const int lane = threadIdx.x & 63;
  const int row = blockIdx.x * 4 + wave;               // 0..16383
  const float* src = (row < NROWS)
                         ? userw + (size_t)row * LDIM
                         : itemw + (size_t)(row - NROWS) * LDIM;

  const float4 v = reinterpret_cast<const float4*>(src)[lane];
  float ss = v.x * v.x + v.y * v.y + v.z * v.z + v.w * v.w;
#pragma unroll
  for (int off = 32; off; off >>= 1) ss += __shfl_xor(ss, off, 64);
  const float rn = 1.0f / fmaxf(sqrtf(ss), 1e-8f);

  ushort4 o;
  o.x = f2bf_rne(v.x * rn);
  o.y = f2bf_rne(v.y * rn);
  o.z = f2bf_rne(v.z * rn);
  o.w = f2bf_rne(v.w * rn);
  reinterpret_cast<ushort4*>(dst + (size_t)row * LDIM)[lane] = o;
}

__device__ __forceinline__ void gld_lds16(const __bf16* g, __bf16* l) {
  __builtin_amdgcn_global_load_lds(
      (const __attribute__((address_space(1))) uint32_t*)g,
      (__attribute__((address_space(3))) uint32_t*)l, 16, 0, 0);
}

// NT GEMM: C[8192][8192] f32 = A[8192][256] * B[8192][256]^T, bf16 inputs.
__global__ __launch_bounds__(256) void cos_gemm(
    const __bf16* __restrict__ A, const __bf16* __restrict__ B,
    float* __restrict__ C) {
  // As/Bs (compute phase) and ep (epilogue phase) never live simultaneously:
  // ep is first written after the compute loop's final __syncthreads().
  __shared__ union {
    struct {
      __bf16 As[BM][BK];   // 8 KB
      __bf16 Bs[BN][BK];   // 8 KB
    } s;
    float ep[32][132];     // 16.5 KB epilogue transpose buffer
  } u;                     // 16.9 KB total -> 8 blocks/CU (wave-limited)

  const int tid  = threadIdx.x;
  const int wid  = tid >> 6;
  const int lane = tid & 63;
  const int bn = blockIdx.x;
  const int bm = blockIdx.y;
  const int wr = wid >> 1;        // wave row (0..1) -> 64-row slab
  const int wc = wid & 1;         // wave col (0..1) -> 64-col slab

  // Staging map (R1-exact): LDS dest is wave-uniform base + lane*16.
  const int m0 = (wid << 5) + (lane >> 2);   // + c*16 per call
  const int k0 = (lane & 3) << 3;

  const __bf16* gA = A + (size_t)(bm * BM + m0) * LDIM + k0;
  const __bf16* gB = B + (size_t)(bn * BN + m0) * LDIM + k0;
  __bf16* lA = &u.s.As[0][0] + (wid << 10);
  __bf16* lB = &u.s.Bs[0][0] + (wid << 10);

  const int fr = lane & 15;         // C-row within fragment (swapped mfma)
  const int q = lane >> 4;          // 0..3
  const int kq = q << 3;            // k-offset of this lane's 8 elems

  f32x4 acc[4][4] = {};

  for (int kt = 0; kt < LDIM / BK; ++kt) {
    const int ko = kt * BK;
#pragma unroll
    for (int c = 0; c < 2; ++c) {
      gld_lds16(gA + (size_t)(c * 16) * LDIM + ko, lA + (c << 9));
      gld_lds16(gB + (size_t)(c * 16) * LDIM + ko, lB + (c << 9));
    }
    __syncthreads();

    bf16x8 af[4], bv[4];
#pragma unroll
    for (int m = 0; m < 4; ++m)
      af[m] =
          *reinterpret_cast<const bf16x8*>(&u.s.As[wr * 64 + m * 16 + fr][kq]);
#pragma unroll
    for (int n = 0; n < 4; ++n)
      bv[n] =
          *reinterpret_cast<const bf16x8*>(&u.s.Bs[wc * 64 + n * 16 + fr][kq]);

    // Swapped operands (R2-validated): lane fr = C-row (user), regs = 4
    // consecutive C-cols (item) at q*4.
#pragma unroll
    for (int m = 0; m < 4; ++m)
#pragma unroll
      for (int n = 0; n < 4; ++n)
        acc[m][n] = __builtin_amdgcn_mfma_f32_16x16x32_bf16(bv[n], af[m],
                                                            acc[m][n], 0, 0, 0);
    __syncthreads();   // last iteration: As/Bs reads complete -> ep may reuse
  }

  // ---- full-line NONTEMPORAL store epilogue (R8-exact, ep = union) -------
  float* Cbase = C + (size_t)(bm * BM) * NDIM + bn * BN;
#pragma unroll
  for (int p = 0; p < 4; ++p) {
#pragma unroll
    for (int n = 0; n < 4; ++n)
      *reinterpret_cast<f32x4*>(
          &u.ep[wr * 16 + fr][wc * 64 + n * 16 + (q << 2)]) = acc[p][n];
    __syncthreads();
#pragma unroll
    for (int s = 0; s < 4; ++s) {
      const int r = s * 8 + (tid >> 5);                       // LDS row 0..31
      const int grow = ((r >> 4) << 6) + (p << 4) + (r & 15); // tile row
      const f32x4 v =
          *reinterpret_cast<const f32x4*>(&u.ep[r][(tid & 31) << 2]);
      __builtin_nontemporal_store(
          v, reinterpret_cast<f32x4*>(Cbase + (size_t)grow * NDIM +
                                      ((tid & 31) << 2)));
    }
    __syncthreads();   // protect ep before next pass overwrites
  }
}

extern "C" void kernel_launch(void* const* d_in, const int* in_sizes, int n_in,
                              void* d_out, int out_size, void* d_ws, size_t ws_size,
                              hipStream_t stream) {
  const float* user_w = (const float*)d_in[0];
  const float* item_w = (const float*)d_in[1];
  // d_in[2], d_in[3]: indices (unused on test path); d_in[4]: is_test == 1.
  float* out = (float*)d_out;

  unsigned short* un = (unsigned short*)d_ws;             // 4 MB
  unsigned short* vn = un + (size_t)NROWS * LDIM;         // 4 MB

  normalize_both<<<(2 * NROWS) / 4, 256, 0, stream>>>(user_w, item_w, un);

  dim3 grid(NDIM / BN, NDIM / BM);
  cos_gemm<<<grid, 256, 0, stream>>>((const __bf16*)un, (const __bf16*)vn, out);
}

// Round 11
// 76.918 us; speedup vs baseline: 2.0624x; 2.0624x over previous
//
#include <hip/hip_runtime.h>
#include <hip/hip_bf16.h>
#include <stdint.h>

// ---------------------------------------------------------------------------
// MF cosine-similarity, test path:
//   C[u][i] = Un[u].Vn[i]; Un/Vn = fp32-normalized rows rounded to bf16.
//
// R11 = R8 (72.5us, best) + ONE change: BM 128 -> 256 (BN stays 128).
//   Traffic model: staged reads per output byte drop 2.0 -> 1.5
//   (512 MB -> 384 MB); the GEMM is fabric-traffic-bound (~13 TB/s mixed
//   sustained), so bytes -- not schedule -- set the time. All proven parts
//   kept verbatim: BK=32, 2-barrier loop, no prefetch, swapped-operand MFMA
//   acc[4][4]/wave, nt stores, full-line LDS-transpose epilogue (separate
//   buffer -- R10's union was a disaster), 16 waves/CU via launch_bounds.
// ---------------------------------------------------------------------------

#define LDIM 256
#define NROWS 8192
#define NDIM 8192
#define BM 256
#define BN 128
#define BK 32

typedef __bf16 bf16x8 __attribute__((ext_vector_type(8)));
typedef float f32x4 __attribute__((ext_vector_type(4)));

__device__ __forceinline__ unsigned short f2bf_rne(float f) {
  union { float f; uint32_t u; } c;
  c.f = f;
  uint32_t u = c.u;
  u += 0x7FFFu + ((u >> 16) & 1u);   // round-to-nearest-even
  return (unsigned short)(u >> 16);
}

// One wave per row, both tables in one launch: 256 f32 -> norm -> 256 bf16.
__global__ __launch_bounds__(256) void normalize_both(
    const float* __restrict__ userw, const float* __restrict__ itemw,
    unsigned short* __restrict__ dst) {
  const int wave = threadIdx.x >> 6;
  const int lane = threadIdx.x & 63;
  const int row = blockIdx.x * 4 + wave;               // 0..16383
  const float* src = (row < NROWS)
                         ? userw + (size_t)row * LDIM
                         : itemw + (size_t)(row - NROWS) * LDIM;

  const float4 v = reinterpret_cast<const float4*>(src)[lane];
  float ss = v.x * v.x + v.y * v.y + v.z * v.z + v.w * v.w;
#pragma unroll
  for (int off = 32; off; off >>= 1) ss += __shfl_xor(ss, off, 64);
  const float rn = 1.0f / fmaxf(sqrtf(ss), 1e-8f);

  ushort4 o;
  o.x = f2bf_rne(v.x * rn);
  o.y = f2bf_rne(v.y * rn);
  o.z = f2bf_rne(v.z * rn);
  o.w = f2bf_rne(v.w * rn);
  reinterpret_cast<ushort4*>(dst + (size_t)row * LDIM)[lane] = o;
}

__device__ __forceinline__ void gld_lds16(const __bf16* g, __bf16* l) {
  __builtin_amdgcn_global_load_lds(
      (const __attribute__((address_space(1))) uint32_t*)g,
      (__attribute__((address_space(3))) uint32_t*)l, 16, 0, 0);
}

// NT GEMM: C[8192][8192] f32 = A[8192][256] * B[8192][256]^T, bf16 inputs.
// 512 threads = 8 waves mapped 4x2 over a 256x128 tile (64x64 per wave).
__global__ __launch_bounds__(512, 4) void cos_gemm(
    const __bf16* __restrict__ A, const __bf16* __restrict__ B,
    float* __restrict__ C) {
  __shared__ __bf16 As[BM * BK];   // 16 KB
  __shared__ __bf16 Bs[BN * BK];   // 8 KB
  __shared__ float ep[64][132];    // 33 KB epilogue transpose (NOT a union)

  const int tid  = threadIdx.x;
  const int wid  = tid >> 6;          // 0..7
  const int lane = tid & 63;
  const int bn = blockIdx.x;          // 0..63
  const int bm = blockIdx.y;          // 0..31
  const int wr = wid >> 1;            // 0..3 -> 64-row slab
  const int wc = wid & 1;             // 0..1 -> 64-col slab

  // Staging map: chunk c (16B) -> row c>>2, k8 = (c&3)*8; LDS elem = c*8.
  // A: 1024 chunks = tid + 512*ci; B: 512 chunks = tid.
  const int srow = tid >> 2;
  const int sk = (tid & 3) << 3;
  const __bf16* gA = A + (size_t)(bm * BM + srow) * LDIM + sk;   // +128 rows @ci=1
  const __bf16* gB = B + (size_t)(bn * BN + srow) * LDIM + sk;
  __bf16* lA = As + tid * 8;          // + 4096 elems @ci=1 (wave-uniform+lane*16)
  __bf16* lB = Bs + tid * 8;

  const int fr = lane & 15;           // C-row within fragment (swapped mfma)
  const int q = lane >> 4;            // 0..3
  const int kq = q << 3;

  f32x4 acc[4][4] = {};

  for (int kt = 0; kt < LDIM / BK; ++kt) {
    const int ko = kt * BK;
    gld_lds16(gA + ko, lA);
    gld_lds16(gA + (size_t)128 * LDIM + ko, lA + 4096);
    gld_lds16(gB + ko, lB);
    __syncthreads();

    bf16x8 af[4], bv[4];
#pragma unroll
    for (int m = 0; m < 4; ++m)
      af[m] = *reinterpret_cast<const bf16x8*>(
          &As[(wr * 64 + m * 16 + fr) * BK + kq]);
#pragma unroll
    for (int n = 0; n < 4; ++n)
      bv[n] = *reinterpret_cast<const bf16x8*>(
          &Bs[(wc * 64 + n * 16 + fr) * BK + kq]);

    // Swapped operands (R2-validated): lane fr = C-row (user), regs = 4
    // consecutive C-cols (item) at q*4.
#pragma unroll
    for (int m = 0; m < 4; ++m)
#pragma unroll
      for (int n = 0; n < 4; ++n)
        acc[m][n] = __builtin_amdgcn_mfma_f32_16x16x32_bf16(bv[n], af[m],
                                                            acc[m][n], 0, 0, 0);
    __syncthreads();
  }

  // ---- full-line NONTEMPORAL store epilogue -------------------------------
  // Pass s stages the 64-row slab owned by waves with wr==s (all m,n frags),
  // then all 512 threads store 64 rows x 512B fully-contiguous spans.
  float* Cbase = C + (size_t)(bm * BM) * NDIM + bn * BN;
#pragma unroll
  for (int s = 0; s < 4; ++s) {
    if (wr == s) {
#pragma unroll
      for (int m = 0; m < 4; ++m)
#pragma unroll
        for (int n = 0; n < 4; ++n)
          *reinterpret_cast<f32x4*>(
              &ep[m * 16 + fr][wc * 64 + n * 16 + (q << 2)]) = acc[m][n];
    }
    __syncthreads();
#pragma unroll
    for (int s2 = 0; s2 < 4; ++s2) {
      const int c = tid + 512 * s2;          // 2048 chunks = 64 rows x 32
      const int r = c >> 5;                  // 0..63
      const int col = (c & 31) << 2;         // 0..124
      const f32x4 v = *reinterpret_cast<const f32x4*>(&ep[r][col]);
      __builtin_nontemporal_store(
          v, reinterpret_cast<f32x4*>(Cbase + (size_t)(s * 64 + r) * NDIM + col));
    }
    __syncthreads();   // protect ep before next pass overwrites
  }
}

extern "C" void kernel_launch(void* const* d_in, const int* in_sizes, int n_in,
                              void* d_out, int out_size, void* d_ws, size_t ws_size,
                              hipStream_t stream) {
  const float* user_w = (const float*)d_in[0];
  const float* item_w = (const float*)d_in[1];
  // d_in[2], d_in[3]: indices (unused on test path); d_in[4]: is_test == 1.
  float* out = (float*)d_out;

  unsigned short* un = (unsigned short*)d_ws;             // 4 MB
  unsigned short* vn = un + (size_t)NROWS * LDIM;         // 4 MB

  normalize_both<<<(2 * NROWS) / 4, 256, 0, stream>>>(user_w, item_w, un);

  dim3 grid(NDIM / BN, NDIM / BM);
  cos_gemm<<<grid, 512, 0, stream>>>((const __bf16*)un, (const __bf16*)vn, out);
}

// Round 12
// 75.828 us; speedup vs baseline: 2.0921x; 1.0144x over previous
//
#include <hip/hip_runtime.h>
#include <hip/hip_bf16.h>
#include <stdint.h>

// ---------------------------------------------------------------------------
// MF cosine-similarity, test path:
//   C[u][i] = Un[u].Vn[i]; Un/Vn = fp32-normalized rows rounded to bf16.
//
// R12 = R8 (72.5us, best) with ONE variable changed: tile aspect
// 128x128 -> 64x256, so each block's nt-store spans are 1KB contiguous
// per C-row instead of 512B (DRAM-burst theory; R9 proved 64B<<512B under
// nt, 1KB untested). Held fixed from R8: 256 threads, 4 waves, per-wave
// acc[4][4] swapped-operand MFMA, BK=32 2-barrier loop, nt + full-line
// LDS-transpose epilogue, 4 blk/CU / 16 waves/CU, 4096 blocks, x-major
// dispatch (resident B working set ~512KB/XCD, same as R8).
// Cost side: staged bytes per output byte 2.0 -> 2.5 (mostly L2-absorbed).
// ---------------------------------------------------------------------------

#define LDIM 256
#define NROWS 8192
#define NDIM 8192
#define BM 64
#define BN 256
#define BK 32

typedef __bf16 bf16x8 __attribute__((ext_vector_type(8)));
typedef float f32x4 __attribute__((ext_vector_type(4)));

__device__ __forceinline__ unsigned short f2bf_rne(float f) {
  union { float f; uint32_t u; } c;
  c.f = f;
  uint32_t u = c.u;
  u += 0x7FFFu + ((u >> 16) & 1u);   // round-to-nearest-even
  return (unsigned short)(u >> 16);
}

// One wave per row, both tables in one launch: 256 f32 -> norm -> 256 bf16.
__global__ __launch_bounds__(256) void normalize_both(
    const float* __restrict__ userw, const float* __restrict__ itemw,
    unsigned short* __restrict__ dst) {
  const int wave = threadIdx.x >> 6;
  const int lane = threadIdx.x & 63;
  const int row = blockIdx.x * 4 + wave;               // 0..16383
  const float* src = (row < NROWS)
                         ? userw + (size_t)row * LDIM
                         : itemw + (size_t)(row - NROWS) * LDIM;

  const float4 v = reinterpret_cast<const float4*>(src)[lane];
  float ss = v.x * v.x + v.y * v.y + v.z * v.z + v.w * v.w;
#pragma unroll
  for (int off = 32; off; off >>= 1) ss += __shfl_xor(ss, off, 64);
  const float rn = 1.0f / fmaxf(sqrtf(ss), 1e-8f);

  ushort4 o;
  o.x = f2bf_rne(v.x * rn);
  o.y = f2bf_rne(v.y * rn);
  o.z = f2bf_rne(v.z * rn);
  o.w = f2bf_rne(v.w * rn);
  reinterpret_cast<ushort4*>(dst + (size_t)row * LDIM)[lane] = o;
}

__device__ __forceinline__ void gld_lds16(const __bf16* g, __bf16* l) {
  __builtin_amdgcn_global_load_lds(
      (const __attribute__((address_space(1))) uint32_t*)g,
      (__attribute__((address_space(3))) uint32_t*)l, 16, 0, 0);
}

// NT GEMM: C[8192][8192] f32 = A[8192][256] * B[8192][256]^T, bf16 inputs.
// 256 threads = 4 waves; tile 64x256; wave w owns rows 0..63, cols w*64..+64.
__global__ __launch_bounds__(256) void cos_gemm(
    const __bf16* __restrict__ A, const __bf16* __restrict__ B,
    float* __restrict__ C) {
  __shared__ __bf16 As[BM * BK];   // 4 KB
  __shared__ __bf16 Bs[BN * BK];   // 16 KB
  __shared__ float ep[16][260];    // 16.6 KB epilogue transpose buffer

  const int tid  = threadIdx.x;
  const int wid  = tid >> 6;          // 0..3 -> 64-col slab
  const int lane = tid & 63;
  const int bn = blockIdx.x;          // 0..31  (x-major: bn fastest)
  const int bm = blockIdx.y;          // 0..127

  // Staging map: chunk (16B) -> row c>>2, k8 = (c&3)*8; LDS elem = c*8.
  // A: 256 chunks = tid; B: 1024 chunks = tid + 256*ci, ci=0..3.
  const int srow = tid >> 2;          // 0..63
  const int sk = (tid & 3) << 3;
  const __bf16* gA = A + (size_t)(bm * BM + srow) * LDIM + sk;
  const __bf16* gB = B + (size_t)(bn * BN + srow) * LDIM + sk;  // +64 rows/ci
  __bf16* lA = As + tid * 8;
  __bf16* lB = Bs + tid * 8;          // + 2048 elems per ci

  const int fr = lane & 15;           // C-row within fragment (swapped mfma)
  const int q = lane >> 4;            // 0..3
  const int kq = q << 3;

  f32x4 acc[4][4] = {};

  for (int kt = 0; kt < LDIM / BK; ++kt) {
    const int ko = kt * BK;
    gld_lds16(gA + ko, lA);
#pragma unroll
    for (int ci = 0; ci < 4; ++ci)
      gld_lds16(gB + (size_t)(ci * 64) * LDIM + ko, lB + ci * 2048);
    __syncthreads();

    bf16x8 af[4], bv[4];
#pragma unroll
    for (int m = 0; m < 4; ++m)
      af[m] = *reinterpret_cast<const bf16x8*>(&As[(m * 16 + fr) * BK + kq]);
#pragma unroll
    for (int n = 0; n < 4; ++n)
      bv[n] = *reinterpret_cast<const bf16x8*>(
          &Bs[(wid * 64 + n * 16 + fr) * BK + kq]);

    // Swapped operands (R2-validated): lane fr = C-row (user), regs = 4
    // consecutive C-cols (item) at q*4.
#pragma unroll
    for (int m = 0; m < 4; ++m)
#pragma unroll
      for (int n = 0; n < 4; ++n)
        acc[m][n] = __builtin_amdgcn_mfma_f32_16x16x32_bf16(bv[n], af[m],
                                                            acc[m][n], 0, 0, 0);
    __syncthreads();
  }

  // ---- full-line NONTEMPORAL store epilogue ------------------------------
  // Pass p: all waves stage C-rows p*16..p*16+15 (16 rows x 256 cols), then
  // 1024 f32x4 chunks stored as 16 rows x 1KB fully-contiguous spans.
  float* Cbase = C + (size_t)(bm * BM) * NDIM + bn * BN;
#pragma unroll
  for (int p = 0; p < 4; ++p) {
#pragma unroll
    for (int n = 0; n < 4; ++n)
      *reinterpret_cast<f32x4*>(&ep[fr][wid * 64 + n * 16 + (q << 2)]) =
          acc[p][n];
    __syncthreads();
#pragma unroll
    for (int s2 = 0; s2 < 4; ++s2) {
      const int c = tid + 256 * s2;          // 1024 chunks = 16 rows x 64
      const int r = c >> 6;                  // 0..15
      const int col = (c & 63) << 2;         // 0..252
      const f32x4 v = *reinterpret_cast<const f32x4*>(&ep[r][col]);
      __builtin_nontemporal_store(
          v, reinterpret_cast<f32x4*>(Cbase + (size_t)(p * 16 + r) * NDIM + col));
    }
    __syncthreads();   // protect ep before next pass overwrites
  }
}

extern "C" void kernel_launch(void* const* d_in, const int* in_sizes, int n_in,
                              void* d_out, int out_size, void* d_ws, size_t ws_size,
                              hipStream_t stream) {
  const float* user_w = (const float*)d_in[0];
  const float* item_w = (const float*)d_in[1];
  // d_in[2], d_in[3]: indices (unused on test path); d_in[4]: is_test == 1.
  float* out = (float*)d_out;

  unsigned short* un = (unsigned short*)d_ws;             // 4 MB
  unsigned short* vn = un + (size_t)NROWS * LDIM;         // 4 MB

  normalize_both<<<(2 * NROWS) / 4, 256, 0, stream>>>(user_w, item_w, un);

  dim3 grid(NDIM / BN, NDIM / BM);
  cos_gemm<<<grid, 256, 0, stream>>>((const __bf16*)un, (const __bf16*)vn, out);
}

// Round 13
// 72.267 us; speedup vs baseline: 2.1952x; 1.0493x over previous
//
#include <hip/hip_runtime.h>
#include <hip/hip_bf16.h>
#include <stdint.h>

// ---------------------------------------------------------------------------
// MF cosine-similarity, test path:
//   C[u][i] = Un[u].Vn[i]; Un/Vn = fp32-normalized rows rounded to bf16.
//
// R13 = R8 VERBATIM RESTORE (best measured: 72.5us).
//   Final configuration after 12 probes: BK=32 / 4-wave / 128x128 tile /
//   2-barrier loop (no prefetch -- all schedule surgery regressed),
//   swapped-operand MFMA, NONTEMPORAL stores via full-line LDS-transpose
//   epilogue (nt requires >=512B-contiguous spans: R9 proved 64B chunks
//   collapse under nt; R12 proved 1KB buys nothing over 512B),
//   4 blk/CU (R9/R10 proved higher residency craters L2 reuse).
//   Effective mixed HBM rate ~4.9 TB/s vs 6.9 TB/s pure-fill = ~71%,
//   i.e. at the practical mixed read+write roofline for this traffic mix
//   (352 MB unavoidable HBM bytes).
// ---------------------------------------------------------------------------

#define LDIM 256
#define NROWS 8192
#define NDIM 8192
#define BM 128
#define BN 128
#define BK 32

typedef __bf16 bf16x8 __attribute__((ext_vector_type(8)));
typedef float f32x4 __attribute__((ext_vector_type(4)));

__device__ __forceinline__ unsigned short f2bf_rne(float f) {
  union { float f; uint32_t u; } c;
  c.f = f;
  uint32_t u = c.u;
  u += 0x7FFFu + ((u >> 16) & 1u);   // round-to-nearest-even
  return (unsigned short)(u >> 16);
}

// One wave per row, both tables in one launch: 256 f32 -> norm -> 256 bf16.
__global__ __launch_bounds__(256) void normalize_both(
    const float* __restrict__ userw, const float* __restrict__ itemw,
    unsigned short* __restrict__ dst) {
  const int wave = threadIdx.x >> 6;
  const int lane = threadIdx.x & 63;
  const int row = blockIdx.x * 4 + wave;               // 0..16383
  const float* src = (row < NROWS)
                         ? userw + (size_t)row * LDIM
                         : itemw + (size_t)(row - NROWS) * LDIM;

  const float4 v = reinterpret_cast<const float4*>(src)[lane];
  float ss = v.x * v.x + v.y * v.y + v.z * v.z + v.w * v.w;
#pragma unroll
  for (int off = 32; off; off >>= 1) ss += __shfl_xor(ss, off, 64);
  const float rn = 1.0f / fmaxf(sqrtf(ss), 1e-8f);

  ushort4 o;
  o.x = f2bf_rne(v.x * rn);
  o.y = f2bf_rne(v.y * rn);
  o.z = f2bf_rne(v.z * rn);
  o.w = f2bf_rne(v.w * rn);
  reinterpret_cast<ushort4*>(dst + (size_t)row * LDIM)[lane] = o;
}

__device__ __forceinline__ void gld_lds16(const __bf16* g, __bf16* l) {
  __builtin_amdgcn_global_load_lds(
      (const __attribute__((address_space(1))) uint32_t*)g,
      (__attribute__((address_space(3))) uint32_t*)l, 16, 0, 0);
}

// NT GEMM: C[8192][8192] f32 = A[8192][256] * B[8192][256]^T, bf16 inputs.
__global__ __launch_bounds__(256) void cos_gemm(
    const __bf16* __restrict__ A, const __bf16* __restrict__ B,
    float* __restrict__ C) {
  __shared__ __bf16 As[BM][BK];      // 8 KB
  __shared__ __bf16 Bs[BN][BK];      // 8 KB
  __shared__ float ep[32][132];      // 16.5 KB epilogue transpose buffer

  const int tid  = threadIdx.x;
  const int wid  = tid >> 6;
  const int lane = tid & 63;
  const int bn = blockIdx.x;
  const int bm = blockIdx.y;
  const int wr = wid >> 1;        // wave row (0..1) -> 64-row slab
  const int wc = wid & 1;         // wave col (0..1) -> 64-col slab

  // Staging map (R1-exact): LDS dest is wave-uniform base + lane*16.
  const int m0 = (wid << 5) + (lane >> 2);   // + c*16 per call
  const int k0 = (lane & 3) << 3;

  const __bf16* gA = A + (size_t)(bm * BM + m0) * LDIM + k0;
  const __bf16* gB = B + (size_t)(bn * BN + m0) * LDIM + k0;
  __bf16* lA = &As[0][0] + (wid << 10);
  __bf16* lB = &Bs[0][0] + (wid << 10);

  const int fr = lane & 15;         // C-row within fragment (swapped mfma)
  const int q = lane >> 4;          // 0..3
  const int kq = q << 3;            // k-offset of this lane's 8 elems

  f32x4 acc[4][4] = {};

  for (int kt = 0; kt < LDIM / BK; ++kt) {
    const int ko = kt * BK;
#pragma unroll
    for (int c = 0; c < 2; ++c) {
      gld_lds16(gA + (size_t)(c * 16) * LDIM + ko, lA + (c << 9));
      gld_lds16(gB + (size_t)(c * 16) * LDIM + ko, lB + (c << 9));
    }
    __syncthreads();

    bf16x8 af[4], bv[4];
#pragma unroll
    for (int m = 0; m < 4; ++m)
      af[m] = *reinterpret_cast<const bf16x8*>(&As[wr * 64 + m * 16 + fr][kq]);
#pragma unroll
    for (int n = 0; n < 4; ++n)
      bv[n] = *reinterpret_cast<const bf16x8*>(&Bs[wc * 64 + n * 16 + fr][kq]);

    // Swapped operands (R2-validated): lane fr = C-row (user), regs = 4
    // consecutive C-cols (item) at q*4.
#pragma unroll
    for (int m = 0; m < 4; ++m)
#pragma unroll
      for (int n = 0; n < 4; ++n)
        acc[m][n] = __builtin_amdgcn_mfma_f32_16x16x32_bf16(bv[n], af[m],
                                                            acc[m][n], 0, 0, 0);
    __syncthreads();
  }

  // ---- full-line NONTEMPORAL store epilogue ------------------------------
  float* Cbase = C + (size_t)(bm * BM) * NDIM + bn * BN;
#pragma unroll
  for (int p = 0; p < 4; ++p) {
#pragma unroll
    for (int n = 0; n < 4; ++n)
      *reinterpret_cast<f32x4*>(&ep[wr * 16 + fr][wc * 64 + n * 16 + (q << 2)]) =
          acc[p][n];
    __syncthreads();
#pragma unroll
    for (int s = 0; s < 4; ++s) {
      const int r = s * 8 + (tid >> 5);                       // LDS row 0..31
      const int grow = ((r >> 4) << 6) + (p << 4) + (r & 15); // tile row
      const f32x4 v = *reinterpret_cast<const f32x4*>(&ep[r][(tid & 31) << 2]);
      __builtin_nontemporal_store(
          v, reinterpret_cast<f32x4*>(Cbase + (size_t)grow * NDIM +
                                      ((tid & 31) << 2)));
    }
    __syncthreads();   // protect ep before next pass overwrites
  }
}

extern "C" void kernel_launch(void* const* d_in, const int* in_sizes, int n_in,
                              void* d_out, int out_size, void* d_ws, size_t ws_size,
                              hipStream_t stream) {
  const float* user_w = (const float*)d_in[0];
  const float* item_w = (const float*)d_in[1];
  // d_in[2], d_in[3]: indices (unused on test path); d_in[4]: is_test == 1.
  float* out = (float*)d_out;

  unsigned short* un = (unsigned short*)d_ws;             // 4 MB
  unsigned short* vn = un + (size_t)NROWS * LDIM;         // 4 MB

  normalize_both<<<(2 * NROWS) / 4, 256, 0, stream>>>(user_w, item_w, un);

  dim3 grid(NDIM / BN, NDIM / BM);
  cos_gemm<<<grid, 256, 0, stream>>>((const __bf16*)un, (const __bf16*)vn, out);
}